// Round 1
// baseline (116.579 us; speedup 1.0000x reference)
//
#include <hip/hip_runtime.h>

// Problem constants (T,B,C)=(2048,2,1024), weight (H,1,K)=(16,1,31), P=15.
#define T_DIM 2048
#define B_DIM 2
#define C_DIM 1024
#define H_DIM 16
#define K_DIM 31
#define P_PAD 15
#define BC    (B_DIM * C_DIM)   // 2048 columns, contiguous for fixed t
#define TT    32                // t-tile per thread in conv kernel

typedef float v4f __attribute__((ext_vector_type(4)));

// ---------------- kernel 1: per-head softmax of (H,K) weights -> d_ws ----
__global__ void k_softmax(const float* __restrict__ w, float* __restrict__ wsm) {
    int h = threadIdx.x;
    if (h < H_DIM) {
        float v[K_DIM];
        float m = -1e30f;
#pragma unroll
        for (int k = 0; k < K_DIM; ++k) { v[k] = w[h * K_DIM + k]; m = fmaxf(m, v[k]); }
        float s = 0.f;
#pragma unroll
        for (int k = 0; k < K_DIM; ++k) { v[k] = expf(v[k] - m); s += v[k]; }
        float inv = 1.f / s;
#pragma unroll
        for (int k = 0; k < K_DIM; ++k) wsm[h * K_DIM + k] = v[k] * inv;
    }
}

// ---------------- kernel 2: depthwise 'same' conv over t ------------------
// out[t, col] = sum_k w[h(col), k] * x[t - P + k, col],  col = b*C + c
// Thread owns one column, computes TT consecutive t's with a register
// sliding window (fully unrolled -> static indices -> pure VGPRs).
__global__ __launch_bounds__(256) void k_conv(const float* __restrict__ x,
                                              const float* __restrict__ wsm,
                                              float* __restrict__ out) {
    const int col = blockIdx.x * 256 + threadIdx.x;  // [0, 2048)
    const int t0  = blockIdx.y * TT;
    const int c   = col & (C_DIM - 1);
    const int h   = c >> 6;                          // R = C/H = 64; wave-uniform

    float wr[K_DIM];
#pragma unroll
    for (int k = 0; k < K_DIM; ++k) wr[k] = wsm[h * K_DIM + k];

    float xv[TT + K_DIM - 1];                        // 62 values
#pragma unroll
    for (int r = 0; r < TT + K_DIM - 1; ++r) {
        int t = t0 - P_PAD + r;                      // wave-uniform bounds test
        xv[r] = (t >= 0 && t < T_DIM) ? x[t * BC + col] : 0.f;
    }

#pragma unroll
    for (int i = 0; i < TT; ++i) {
        float acc = 0.f;
#pragma unroll
        for (int k = 0; k < K_DIM; ++k) acc = fmaf(wr[k], xv[i + k], acc);
        out[(t0 + i) * BC + col] = acc;
    }
}

// ---------------- kernel 3: banded Toeplitz fill (the 537 MB write) -------
// we[bh, i, j] = (0 <= j-i+P < K) ? w[bh&15, j-i+P] : 0
// One float4 per loop iteration, nontemporal streaming stores.
__global__ __launch_bounds__(256) void k_expand(const float* __restrict__ wsm,
                                                float* __restrict__ we) {
    const unsigned N4 = 32u * T_DIM * (T_DIM / 4);   // 33,554,432 float4s
    const unsigned stride = gridDim.x * 256u;
    for (unsigned idx = blockIdx.x * 256u + threadIdx.x; idx < N4; idx += stride) {
        const unsigned bh  = idx >> 20;              // T*T/4 = 2^20 per image
        const unsigned rem = idx & 0xFFFFFu;
        const unsigned i   = rem >> 9;               // T/4 = 512 float4 per row
        const int      j4  = (int)((rem & 511u) << 2);
        const int      d   = j4 - (int)i + P_PAD;    // band offset of elem 0

        v4f v = (v4f)0.f;
        if (d > -4 && d < K_DIM) {                   // any of the 4 in band?
            const float* wrow = wsm + (bh & (H_DIM - 1)) * K_DIM;
            v.x = (d     >= 0 && d     < K_DIM) ? wrow[d]     : 0.f;
            v.y = (d + 1 >= 0 && d + 1 < K_DIM) ? wrow[d + 1] : 0.f;
            v.z = (d + 2 >= 0 && d + 2 < K_DIM) ? wrow[d + 2] : 0.f;
            v.w = (d + 3 >= 0 && d + 3 < K_DIM) ? wrow[d + 3] : 0.f;
        }
        __builtin_nontemporal_store(v, (v4f*)we + idx);
    }
}

extern "C" void kernel_launch(void* const* d_in, const int* in_sizes, int n_in,
                              void* d_out, int out_size, void* d_ws, size_t ws_size,
                              hipStream_t stream) {
    const float* x = (const float*)d_in[0];
    const float* w = (const float*)d_in[1];

    float* out = (float*)d_out;                              // (T,B,C) first
    float* we  = out + (size_t)T_DIM * B_DIM * C_DIM;        // then (B*H,T,T)
    float* wsm = (float*)d_ws;                               // H*K softmaxed weights

    k_softmax<<<1, 64, 0, stream>>>(w, wsm);

    dim3 cgrid(BC / 256, T_DIM / TT);                        // (8, 64)
    k_conv<<<cgrid, 256, 0, stream>>>(x, wsm, out);

    k_expand<<<2048, 256, 0, stream>>>(wsm, we);
}

// Round 2
// 116.092 us; speedup vs baseline: 1.0042x; 1.0042x over previous
//
#include <hip/hip_runtime.h>

// (T,B,C)=(2048,2,1024), weight (H,1,K)=(16,1,31), P=15.
// Single fused kernel: per-block LDS softmax + (conv tile for blocks<512)
// + balanced slice of the 537 MB banded-Toeplitz fill.
#define T_DIM 2048
#define B_DIM 2
#define C_DIM 1024
#define H_DIM 16
#define K_DIM 31
#define P_PAD 15
#define BC    (B_DIM * C_DIM)     // 2048 columns, contiguous for fixed t
#define TT    32                  // t-tile per conv thread

#define CONV_BLOCKS 512           // (BC/256) * (T_DIM/TT) = 8*64 tiles
#define XBLOCKS     2048
#define GRID_BLKS   (CONV_BLOCKS + XBLOCKS)   // 2560
// expand work: 32*T*T/4 = 33,554,432 float4s = 131072 units of 256 float4s.
// conv tile ~ 95KB traffic ~ 24 unit-equivalents -> conv blocks get 32 units,
// pure-expand blocks get 56.  512*32 + 2048*56 = 131072 exactly.
#define E1 32u
#define E2 56u

typedef float v4f __attribute__((ext_vector_type(4)));

__global__ __launch_bounds__(256) void k_fused(const float* __restrict__ x,
                                               const float* __restrict__ w,
                                               float* __restrict__ out,
                                               float* __restrict__ we) {
    __shared__ float lw[H_DIM * K_DIM];       // softmaxed weights, all heads
    const int tid = threadIdx.x;

    // ---- per-block softmax (threads 0..15, one head each; ~free) ----
    if (tid < H_DIM) {
        float v[K_DIM];
        float m = -1e30f;
#pragma unroll
        for (int k = 0; k < K_DIM; ++k) { v[k] = w[tid * K_DIM + k]; m = fmaxf(m, v[k]); }
        float s = 0.f;
#pragma unroll
        for (int k = 0; k < K_DIM; ++k) { v[k] = expf(v[k] - m); s += v[k]; }
        float inv = 1.f / s;
#pragma unroll
        for (int k = 0; k < K_DIM; ++k) lw[tid * K_DIM + k] = v[k] * inv;
    }
    __syncthreads();

    const int bid = blockIdx.x;
    unsigned ubase, ucnt;

    if (bid < CONV_BLOCKS) {
        // ---- depthwise conv tile: out[t,col] = sum_k w[h,k] x[t-P+k,col] ----
        const int colBase = (bid & 7) * 256;
        const int t0      = (bid >> 3) * TT;
        const int col     = colBase + tid;
        const int h       = (col & (C_DIM - 1)) >> 6;   // R=64; wave-uniform

        float wr[K_DIM];
#pragma unroll
        for (int k = 0; k < K_DIM; ++k) wr[k] = lw[h * K_DIM + k];

        float xv[TT + K_DIM - 1];                       // 62-value sliding window
#pragma unroll
        for (int r = 0; r < TT + K_DIM - 1; ++r) {
            int t = t0 - P_PAD + r;                     // wave-uniform bounds
            xv[r] = (t >= 0 && t < T_DIM) ? x[t * BC + col] : 0.f;
        }
#pragma unroll
        for (int i = 0; i < TT; ++i) {
            float acc = 0.f;
#pragma unroll
            for (int k = 0; k < K_DIM; ++k) acc = fmaf(wr[k], xv[i + k], acc);
            out[(t0 + i) * BC + col] = acc;
        }
        ubase = (unsigned)bid * E1;  ucnt = E1;
    } else {
        ubase = CONV_BLOCKS * E1 + (unsigned)(bid - CONV_BLOCKS) * E2;  ucnt = E2;
    }

    // ---- banded Toeplitz fill slice (contiguous per block) ----
    // we[bh,i,j] = (0 <= j-i+P < K) ? lw[bh&15, j-i+P] : 0
    v4f* we4 = (v4f*)we;
#pragma unroll 4
    for (unsigned u = 0; u < ucnt; ++u) {
        const unsigned f   = (ubase + u) * 256u + (unsigned)tid;  // float4 index
        const unsigned bh  = f >> 20;               // T*T/4 = 2^20 per image
        const unsigned rem = f & 0xFFFFFu;
        const unsigned i   = rem >> 9;              // 512 float4 per row
        const int      j4  = (int)((rem & 511u) << 2);
        const int      d   = j4 - (int)i + P_PAD;   // band offset of elem 0

        v4f v = (v4f)0.f;
        if (d > -4 && d < K_DIM) {                  // any of the 4 in band?
            const float* wrow = lw + (bh & (H_DIM - 1)) * K_DIM;
            v.x = (d     >= 0 && d     < K_DIM) ? wrow[d]     : 0.f;
            v.y = (d + 1 >= 0 && d + 1 < K_DIM) ? wrow[d + 1] : 0.f;
            v.z = (d + 2 >= 0 && d + 2 < K_DIM) ? wrow[d + 2] : 0.f;
            v.w = (d + 3 >= 0 && d + 3 < K_DIM) ? wrow[d + 3] : 0.f;
        }
        __builtin_nontemporal_store(v, we4 + f);
    }
}

extern "C" void kernel_launch(void* const* d_in, const int* in_sizes, int n_in,
                              void* d_out, int out_size, void* d_ws, size_t ws_size,
                              hipStream_t stream) {
    const float* x = (const float*)d_in[0];
    const float* w = (const float*)d_in[1];
    float* out = (float*)d_out;                          // (T,B,C) first
    float* we  = out + (size_t)T_DIM * B_DIM * C_DIM;    // then (B*H,T,T)

    k_fused<<<GRID_BLKS, 256, 0, stream>>>(x, w, out, we);
}

// Round 3
// 113.974 us; speedup vs baseline: 1.0229x; 1.0186x over previous
//
#include <hip/hip_runtime.h>

// (T,B,C)=(2048,2,1024), weight (H,1,K)=(16,1,31), P=15.
// Single fused kernel: per-block LDS softmax + (conv tile for blocks<512)
// + balanced slice of the 537 MB banded-Toeplitz fill.
// R3 change: PLAIN stores (no nontemporal) for the fill stream — the
// harness's fillBufferAligned proves plain stores hit 6.7 TB/s; our NT
// stores were stuck at ~5.2 TB/s.
#define T_DIM 2048
#define B_DIM 2
#define C_DIM 1024
#define H_DIM 16
#define K_DIM 31
#define P_PAD 15
#define BC    (B_DIM * C_DIM)     // 2048 columns, contiguous for fixed t
#define TT    32                  // t-tile per conv thread

#define CONV_BLOCKS 512           // (BC/256) * (T_DIM/TT) = 8*64 tiles
#define XBLOCKS     2048
#define GRID_BLKS   (CONV_BLOCKS + XBLOCKS)   // 2560
// expand work: 32*T*T/4 = 33,554,432 float4s = 131072 units of 256 float4s.
// 512*32 + 2048*56 = 131072 exactly.
#define E1 32u
#define E2 56u

typedef float v4f __attribute__((ext_vector_type(4)));

__global__ __launch_bounds__(256) void k_fused(const float* __restrict__ x,
                                               const float* __restrict__ w,
                                               float* __restrict__ out,
                                               float* __restrict__ we) {
    __shared__ float lw[H_DIM * K_DIM];       // softmaxed weights, all heads
    const int tid = threadIdx.x;

    // ---- per-block softmax (threads 0..15, one head each; ~free) ----
    if (tid < H_DIM) {
        float v[K_DIM];
        float m = -1e30f;
#pragma unroll
        for (int k = 0; k < K_DIM; ++k) { v[k] = w[tid * K_DIM + k]; m = fmaxf(m, v[k]); }
        float s = 0.f;
#pragma unroll
        for (int k = 0; k < K_DIM; ++k) { v[k] = expf(v[k] - m); s += v[k]; }
        float inv = 1.f / s;
#pragma unroll
        for (int k = 0; k < K_DIM; ++k) lw[tid * K_DIM + k] = v[k] * inv;
    }
    __syncthreads();

    const int bid = blockIdx.x;
    unsigned ubase, ucnt;

    if (bid < CONV_BLOCKS) {
        // ---- depthwise conv tile: out[t,col] = sum_k w[h,k] x[t-P+k,col] ----
        const int colBase = (bid & 7) * 256;
        const int t0      = (bid >> 3) * TT;
        const int col     = colBase + tid;
        const int h       = (col & (C_DIM - 1)) >> 6;   // R=64; wave-uniform

        float wr[K_DIM];
#pragma unroll
        for (int k = 0; k < K_DIM; ++k) wr[k] = lw[h * K_DIM + k];

        float xv[TT + K_DIM - 1];                       // 62-value sliding window
#pragma unroll
        for (int r = 0; r < TT + K_DIM - 1; ++r) {
            int t = t0 - P_PAD + r;                     // wave-uniform bounds
            xv[r] = (t >= 0 && t < T_DIM) ? x[t * BC + col] : 0.f;
        }
#pragma unroll
        for (int i = 0; i < TT; ++i) {
            float acc = 0.f;
#pragma unroll
            for (int k = 0; k < K_DIM; ++k) acc = fmaf(wr[k], xv[i + k], acc);
            out[(t0 + i) * BC + col] = acc;
        }
        ubase = (unsigned)bid * E1;  ucnt = E1;
    } else {
        ubase = CONV_BLOCKS * E1 + (unsigned)(bid - CONV_BLOCKS) * E2;  ucnt = E2;
    }

    // ---- banded Toeplitz fill slice (contiguous per block) ----
    // we[bh,i,j] = (0 <= j-i+P < K) ? lw[bh&15, j-i+P] : 0
    v4f* we4 = (v4f*)we;
#pragma unroll 8
    for (unsigned u = 0; u < ucnt; ++u) {
        const unsigned f   = (ubase + u) * 256u + (unsigned)tid;  // float4 index
        const unsigned bh  = f >> 20;               // T*T/4 = 2^20 per image
        const unsigned rem = f & 0xFFFFFu;
        const unsigned i   = rem >> 9;              // 512 float4 per row
        const int      j4  = (int)((rem & 511u) << 2);
        const int      d   = j4 - (int)i + P_PAD;   // band offset of elem 0

        v4f v = (v4f)0.f;
        if (d > -4 && d < K_DIM) {                  // any of the 4 in band?
            const float* wrow = lw + (bh & (H_DIM - 1)) * K_DIM;
            v.x = (d     >= 0 && d     < K_DIM) ? wrow[d]     : 0.f;
            v.y = (d + 1 >= 0 && d + 1 < K_DIM) ? wrow[d + 1] : 0.f;
            v.z = (d + 2 >= 0 && d + 2 < K_DIM) ? wrow[d + 2] : 0.f;
            v.w = (d + 3 >= 0 && d + 3 < K_DIM) ? wrow[d + 3] : 0.f;
        }
        we4[f] = v;                                 // plain store via L2
    }
}

extern "C" void kernel_launch(void* const* d_in, const int* in_sizes, int n_in,
                              void* d_out, int out_size, void* d_ws, size_t ws_size,
                              hipStream_t stream) {
    const float* x = (const float*)d_in[0];
    const float* w = (const float*)d_in[1];
    float* out = (float*)d_out;                          // (T,B,C) first
    float* we  = out + (size_t)T_DIM * B_DIM * C_DIM;    // then (B*H,T,T)

    k_fused<<<GRID_BLKS, 256, 0, stream>>>(x, w, out, we);
}

// Round 4
// 111.161 us; speedup vs baseline: 1.0487x; 1.0253x over previous
//
#include <hip/hip_runtime.h>

// (T,B,C)=(2048,2,1024), weight (H,1,K)=(16,1,31), P=15.
// Single fused kernel:
//   - per-block LDS softmax of the (16,31) weights (~free)
//   - blocks 0..511: one depthwise-conv tile each (out, 16.8 MB)
//   - ALL 2560 blocks: grid-wide strided sweep filling the 512 MiB banded
//     Toeplitz weight_expanded — same access structure as the harness's
//     fillBufferAligned, which sustains 6.7 TB/s with plain stores.
#define T_DIM 2048
#define B_DIM 2
#define C_DIM 1024
#define H_DIM 16
#define K_DIM 31
#define P_PAD 15
#define BC    (B_DIM * C_DIM)     // 2048 columns, contiguous for fixed t
#define TT    32                  // t-tile per conv thread

#define CONV_BLOCKS 512           // (BC/256) * (T_DIM/TT) = 8*64 tiles
#define GRID_BLKS   2560
#define N4_TOTAL    33554432u     // 32*T*T/4 float4s (512 MiB)
#define SWEEP_STRIDE (GRID_BLKS * 256u)   // 655,360 float4s = 10.5 MB window
#define SWEEP_ITERS  52           // ceil(N4_TOTAL / SWEEP_STRIDE)

typedef float v4f __attribute__((ext_vector_type(4)));

__global__ __launch_bounds__(256) void k_fused(const float* __restrict__ x,
                                               const float* __restrict__ w,
                                               float* __restrict__ out,
                                               float* __restrict__ we) {
    __shared__ float lw[H_DIM * K_DIM];       // softmaxed weights, all heads
    const int tid = threadIdx.x;

    // ---- per-block softmax (threads 0..15, one head each) ----
    if (tid < H_DIM) {
        float v[K_DIM];
        float m = -1e30f;
#pragma unroll
        for (int k = 0; k < K_DIM; ++k) { v[k] = w[tid * K_DIM + k]; m = fmaxf(m, v[k]); }
        float s = 0.f;
#pragma unroll
        for (int k = 0; k < K_DIM; ++k) { v[k] = expf(v[k] - m); s += v[k]; }
        float inv = 1.f / s;
#pragma unroll
        for (int k = 0; k < K_DIM; ++k) lw[tid * K_DIM + k] = v[k] * inv;
    }
    __syncthreads();

    const int bid = blockIdx.x;

    if (bid < CONV_BLOCKS) {
        // ---- depthwise conv tile: out[t,col] = sum_k w[h,k] x[t-P+k,col] ----
        const int colBase = (bid & 7) * 256;
        const int t0      = (bid >> 3) * TT;
        const int col     = colBase + tid;
        const int h       = (col & (C_DIM - 1)) >> 6;   // R=64; wave-uniform

        float wr[K_DIM];
#pragma unroll
        for (int k = 0; k < K_DIM; ++k) wr[k] = lw[h * K_DIM + k];

        float xv[TT + K_DIM - 1];                       // 62-value sliding window
#pragma unroll
        for (int r = 0; r < TT + K_DIM - 1; ++r) {
            int t = t0 - P_PAD + r;                     // wave-uniform bounds
            xv[r] = (t >= 0 && t < T_DIM) ? x[t * BC + col] : 0.f;
        }
#pragma unroll
        for (int i = 0; i < TT; ++i) {
            float acc = 0.f;
#pragma unroll
            for (int k = 0; k < K_DIM; ++k) acc = fmaf(wr[k], xv[i + k], acc);
            out[(t0 + i) * BC + col] = acc;
        }
    }

    // ---- banded Toeplitz fill: grid-wide sweep (fillBuffer pattern) ----
    // we[bh,i,j] = (0 <= j-i+P < K) ? lw[bh&15, j-i+P] : 0
    // Remainder iteration (it=51) covers window positions 0..511; remap so
    // pure-expand blocks (512..1023 -> pos 0..511) own it, not conv blocks.
    unsigned pos = (unsigned)bid + 2048u;
    if (pos >= GRID_BLKS) pos -= GRID_BLKS;
    const unsigned fbase = pos * 256u + (unsigned)tid;

    v4f* we4 = (v4f*)we;
#pragma unroll 4
    for (unsigned it = 0; it < SWEEP_ITERS; ++it) {
        const unsigned f = it * SWEEP_STRIDE + fbase;   // float4 index
        if (f < N4_TOTAL) {
            const unsigned bh  = f >> 20;               // T*T/4 = 2^20 per image
            const unsigned rem = f & 0xFFFFFu;
            const unsigned i   = rem >> 9;              // 512 float4 per row
            const int      j4  = (int)((rem & 511u) << 2);
            const int      d   = j4 - (int)i + P_PAD;   // band offset of elem 0

            v4f v = (v4f)0.f;
            if (d > -4 && d < K_DIM) {                  // any of the 4 in band?
                const float* wrow = lw + (bh & (H_DIM - 1)) * K_DIM;
                v.x = (d     >= 0 && d     < K_DIM) ? wrow[d]     : 0.f;
                v.y = (d + 1 >= 0 && d + 1 < K_DIM) ? wrow[d + 1] : 0.f;
                v.z = (d + 2 >= 0 && d + 2 < K_DIM) ? wrow[d + 2] : 0.f;
                v.w = (d + 3 >= 0 && d + 3 < K_DIM) ? wrow[d + 3] : 0.f;
            }
            we4[f] = v;                                 // plain store via L2
        }
    }
}

extern "C" void kernel_launch(void* const* d_in, const int* in_sizes, int n_in,
                              void* d_out, int out_size, void* d_ws, size_t ws_size,
                              hipStream_t stream) {
    const float* x = (const float*)d_in[0];
    const float* w = (const float*)d_in[1];
    float* out = (float*)d_out;                          // (T,B,C) first
    float* we  = out + (size_t)T_DIM * B_DIM * C_DIM;    // then (B*H,T,T)

    k_fused<<<GRID_BLKS, 256, 0, stream>>>(x, w, out, we);
}

// Round 5
// 107.155 us; speedup vs baseline: 1.0879x; 1.0374x over previous
//
#include <hip/hip_runtime.h>

// (T,B,C)=(2048,2,1024), weight (H,1,K)=(16,1,31), P=15.
// R5 strategy: 98% of weight_expanded is zeros -> hipMemsetAsync (the
// harness-proven 6.65 TB/s fill path) zeroes all 537 MB; then ONE kernel
// writes the conv output + only the band windows (256B aligned full-line
// writes, idempotent zeros in the padding).
#define T_DIM 2048
#define B_DIM 2
#define C_DIM 1024
#define H_DIM 16
#define K_DIM 31
#define P_PAD 15
#define BC    (B_DIM * C_DIM)     // 2048 columns, contiguous for fixed t
#define TT    32                  // t-tile per conv thread

#define CONV_BLOCKS 512           // (BC/256) * (T_DIM/TT) = 8*64 tiles
#define BAND_BLOCKS 256           // 65536 band rows / 256 rows per block
#define GRID_BLKS   (CONV_BLOCKS + BAND_BLOCKS)
#define ROW_BYTES   8192          // T*4 bytes per Toeplitz row

typedef float v4f __attribute__((ext_vector_type(4)));

__global__ __launch_bounds__(256) void k_conv_band(const float* __restrict__ x,
                                                   const float* __restrict__ w,
                                                   float* __restrict__ out,
                                                   float* __restrict__ we) {
    __shared__ float lw[H_DIM * K_DIM];       // softmaxed weights, all heads
    const int tid = threadIdx.x;

    // ---- per-block softmax (threads 0..15, one head each) ----
    if (tid < H_DIM) {
        float v[K_DIM];
        float m = -1e30f;
#pragma unroll
        for (int k = 0; k < K_DIM; ++k) { v[k] = w[tid * K_DIM + k]; m = fmaxf(m, v[k]); }
        float s = 0.f;
#pragma unroll
        for (int k = 0; k < K_DIM; ++k) { v[k] = expf(v[k] - m); s += v[k]; }
        float inv = 1.f / s;
#pragma unroll
        for (int k = 0; k < K_DIM; ++k) lw[tid * K_DIM + k] = v[k] * inv;
    }
    __syncthreads();

    const int bid = blockIdx.x;

    if (bid < CONV_BLOCKS) {
        // ---- depthwise conv tile: out[t,col] = sum_k w[h,k] x[t-P+k,col] ----
        const int colBase = (bid & 7) * 256;
        const int t0      = (bid >> 3) * TT;
        const int col     = colBase + tid;
        const int h       = (col & (C_DIM - 1)) >> 6;   // R=64; wave-uniform

        float wr[K_DIM];
#pragma unroll
        for (int k = 0; k < K_DIM; ++k) wr[k] = lw[h * K_DIM + k];

        float xv[TT + K_DIM - 1];                       // 62-value sliding window
#pragma unroll
        for (int r = 0; r < TT + K_DIM - 1; ++r) {
            int t = t0 - P_PAD + r;                     // wave-uniform bounds
            xv[r] = (t >= 0 && t < T_DIM) ? x[t * BC + col] : 0.f;
        }
#pragma unroll
        for (int i = 0; i < TT; ++i) {
            float acc = 0.f;
#pragma unroll
            for (int k = 0; k < K_DIM; ++k) acc = fmaf(wr[k], xv[i + k], acc);
            out[(t0 + i) * BC + col] = acc;
        }
    } else {
        // ---- band writer: 256 rows per block, 16 lanes per row ----
        // we[bh,i,j] = (0 <= j-i+P < K) ? lw[bh&15, j-i+P] : 0  (band only;
        // everything else already zeroed by the memset).
        // Per row: 256B window aligned to 128B covering the 124B band
        // (slack <=124 + 124 <= 248 < 256; pad bytes are zeros = idempotent).
        const int rowBase = (bid - CONV_BLOCKS) * 256;
        const int sub = tid >> 4;                       // row-in-step [0,16)
        const int l16 = tid & 15;                       // lane within row

#pragma unroll 4
        for (int step = 0; step < 16; ++step) {
            const int r  = rowBase + step * 16 + sub;   // global row [0,65536)
            const int bh = r >> 11;
            const int i  = r & (T_DIM - 1);
            const float* wrow = lw + (bh & (H_DIM - 1)) * K_DIM;

            int s = 4 * i - 60;                         // unclipped band start byte
            if (s < 0) s = 0;
            s &= ~127;                                  // 128B align down
            const int byte0 = s + l16 * 16;
            if (byte0 < ROW_BYTES) {
                const int j0 = byte0 >> 2;              // first col of this lane
                v4f v;
#pragma unroll
                for (int e = 0; e < 4; ++e) {
                    const int d = j0 + e - i + P_PAD;
                    v[e] = (d >= 0 && d < K_DIM) ? wrow[d] : 0.f;
                }
                *(v4f*)((char*)we + ((size_t)r << 13) + byte0) = v;
            }
        }
    }
}

extern "C" void kernel_launch(void* const* d_in, const int* in_sizes, int n_in,
                              void* d_out, int out_size, void* d_ws, size_t ws_size,
                              hipStream_t stream) {
    const float* x = (const float*)d_in[0];
    const float* w = (const float*)d_in[1];
    float* out = (float*)d_out;                          // (T,B,C) first
    float* we  = out + (size_t)T_DIM * B_DIM * C_DIM;    // then (B*H,T,T)

    // Zero the 537 MB Toeplitz buffer via the proven fill path (graph-legal).
    hipMemsetAsync(we, 0, 32ull * T_DIM * T_DIM * sizeof(float), stream);

    k_conv_band<<<GRID_BLKS, 256, 0, stream>>>(x, w, out, we);
}